// Round 9
// baseline (188.335 us; speedup 1.0000x reference)
//
#include <hip/hip_runtime.h>

// SNN spike layer: causal alpha-PSP FIR conv (taps 1..76; srm[0]==0 exactly)
// + sequential refractory threshold scan.
//
// Round-9: all-bits build. Ledger: R8 proved waves_per_eu(1,1) raises the
// allocator ceiling (92->132 VGPR) but float-hist still overflows (~155 live)
// -> spills; AND the +43MB WRITE inflation is identical across builds with
// wildly different spill counts (R0 ~70 over, R7 ~10 over), implicating
// partial-line amplification of the interleaved 80B/chunk output stores
// (tight-store builds R2/R5 were the only ones at exactly-ideal WRITE).
// This build removes BOTH suspects, keeping the fast 1-thread/neuron frame:
//   - history  = 96 bits in 3 VGPRs (R7, verified bit-exact)
//   - OUTPUT   = 300 bits in 10 VGPRs: 320-bit shift register, 10 alignbit
//                + 2 OR per chunk (all compile-time indices -> registers),
//                flushed once at the end in a tight 75x float4 burst so
//                lines merge fully in L2 before eviction
//   - live set ~= 3+10+20(nxt)+20(u)+35(xw)+10(pend)+addr ~= 105 < 132
// No LDS, no barriers, no interleaved global stores in the main loop.
//
// Bit-exactness invariant (absmax must stay 0.0): operands are exactly
// 0.0/1.0 and (float)((bits>>p)&1) reproduces them exactly; each u[t]
// accumulates taps j=1..76 ascending in ONE fmaf chain; scan step identical
// to every verified round. No reassociation anywhere.

#define T_LEN 300
#define CH 20
#define NCHUNK 15          // 15 * 20 == 300 exactly
#define KS 77              // srm kernel length (alpha, tau=10, eps_tol=0.01)
#define KR 10              // ref kernel tail length (K_ref=11 -> 10 pending)
#define THETA_V 10.0f

__global__ __launch_bounds__(256)
__attribute__((amdgpu_waves_per_eu(1, 1)))
void spike_layer_kernel(
    const float* __restrict__ spike_in,
    const float* __restrict__ srm, int srm_len,
    const float* __restrict__ refk, int ref_len,
    float* __restrict__ out, int B)
{
    int b = blockIdx.x * blockDim.x + threadIdx.x;
    if (b >= B) return;

    const float* row  = spike_in + (size_t)b * T_LEN;
    float*       orow = out      + (size_t)b * T_LEN;

    // srm taps (uniform-address loads -> scalarized). Tap 0 == 0.0, skipped.
    float srm_r[KS];
#pragma unroll
    for (int i = 1; i < KS; ++i) srm_r[i] = (i < srm_len) ? srm[i] : 0.0f;

    // refractory tail: ref_kernel[1..], contributions to t+1..t+KR
    float rt[KR];
#pragma unroll
    for (int i = 0; i < KR; ++i) rt[i] = (i + 1 < ref_len) ? refk[i + 1] : 0.0f;

    float pend[KR];
#pragma unroll
    for (int i = 0; i < KR; ++i) pend[i] = 0.0f;

    // 96-bit history window: bit i = x[t0 - 76 + i] for current chunk base t0.
    unsigned w0 = 0, w1 = 0, w2 = 0;   // t < 0 -> no spikes

    // 320-bit output shift register (bit t = spike at time t after final chunk)
    unsigned ob[10];
#pragma unroll
    for (int i = 0; i < 10; ++i) ob[i] = 0u;

    // preload chunk 0
    float nxt[CH];
    {
        const float4* p = (const float4*)row;
#pragma unroll
        for (int i = 0; i < CH / 4; ++i) {
            float4 v = p[i];
            nxt[4*i+0] = v.x; nxt[4*i+1] = v.y; nxt[4*i+2] = v.z; nxt[4*i+3] = v.w;
        }
    }

#pragma unroll 1           // keep the ~2.2k-inst body I-cache resident
    for (int ch = 0; ch < NCHUNK; ++ch) {
        // pack current chunk to bits: x is exactly 0.0f or 1.0f, so IEEE
        // bit 30 (0x3F800000 vs 0x00000000) IS the spike bit.
        unsigned nb = 0;
#pragma unroll
        for (int i = 0; i < CH; ++i)
            nb |= ((__float_as_uint(nxt[i]) >> 30) & 1u) << i;

        // slide history window by 20, install current chunk at bits 76..95
        w0 = (w0 >> 20) | (w1 << 12);
        w1 = (w1 >> 20) | (w2 << 12);
        w2 = (w2 >> 20) | (nb << 12);

        // prefetch next chunk; sched_barrier pins the load issue above the
        // conv so its latency hides under the 1520 FMAs (round-2 lesson).
        if (ch + 1 < NCHUNK) {
            const float4* p = (const float4*)(row + (ch + 1) * CH);
#pragma unroll
            for (int i = 0; i < CH / 4; ++i) {
                float4 v = p[i];
                nxt[4*i+0] = v.x; nxt[4*i+1] = v.y; nxt[4*i+2] = v.z; nxt[4*i+3] = v.w;
            }
        }
        __builtin_amdgcn_sched_barrier(0);

        // conv: u[t0+c] = sum_{j=1}^{76} srm[j] * x[t0+c-j]; operand bit index
        // in window = 76 + c - j. 20 independent FMA chains, taps ascending.
        float u[CH];
#pragma unroll
        for (int c = 0; c < CH; ++c) u[c] = 0.0f;

        // bands 0..3: taps j = 16*bb+1 .. 16*bb+16; window bits [60-16bb, 94-16bb]
#pragma unroll
        for (int bb = 0; bb < 4; ++bb) {
            const int base = 60 - 16 * bb;
            float xw[35];                       // xw[m] = bit(base + m) as f32
#pragma unroll
            for (int m = 0; m < 35; ++m) {
                const int p = base + m;         // compile-time
                const unsigned reg = (p < 32) ? w0 : ((p < 64) ? w1 : w2);
                xw[m] = (float)((reg >> (p & 31)) & 1u);   // v_bfe + v_cvt
            }
#pragma unroll
            for (int d = 1; d <= 16; ++d) {
                const float wt = srm_r[16 * bb + d];
#pragma unroll
                for (int c = 0; c < CH; ++c)
                    u[c] = fmaf(wt, xw[16 - d + c], u[c]);
            }
        }
        // band 4: taps j = 65..76; window bits 0..30 (all in w0)
        {
            float xw[31];
#pragma unroll
            for (int m = 0; m < 31; ++m)
                xw[m] = (float)((w0 >> m) & 1u);
#pragma unroll
            for (int d = 1; d <= 12; ++d) {
                const float wt = srm_r[64 + d];
#pragma unroll
                for (int c = 0; c < CH; ++c)
                    u[c] = fmaf(wt, xw[12 - d + c], u[c]);
            }
        }

        // sequential threshold scan (verified math); spikes go to bit buffer
        unsigned nb_out = 0;
#pragma unroll
        for (int c = 0; c < CH; ++c) {
            const int r = c % KR;      // compile-time (CH == 2*KR)
            float u_eff = u[c] + pend[r];
            bool fire = (u_eff >= THETA_V);
            float s = fire ? 1.0f : 0.0f;
            nb_out |= fire ? (1u << c) : 0u;
#pragma unroll
            for (int i = 0; i < KR - 1; ++i)
                pend[(r + 1 + i) % KR] = fmaf(s, rt[i], pend[(r + 1 + i) % KR]);
            pend[r] = s * rt[KR - 1];  // consumed slot becomes logical tail
        }

        // deposit: shift 320-bit register right by 20, insert at bits 280..299.
        // After the remaining (14-ch) shifts, chunk ch's bit c lands at
        // global bit 20*ch + c == output time t.  All indices compile-time.
#pragma unroll
        for (int i = 0; i < 9; ++i) ob[i] = (ob[i] >> 20) | (ob[i + 1] << 12);
        ob[9] >>= 20;
        ob[8] |= (nb_out & 0xFFu) << 24;   // bits 280..287
        ob[9] |= (nb_out >> 8);            // bits 288..299
    }

    // ---- tight output flush: unpack 300 bits -> 75 float4 stores ----
    // Back-to-back stores let L2 merge full 128B lines before eviction
    // (R2/R5 evidence: tight store phase == exactly-ideal WRITE_SIZE).
#pragma unroll
    for (int w = 0; w < 10; ++w) {
        const int nbits = (w < 9) ? 32 : 12;   // 300 = 9*32 + 12
#pragma unroll
        for (int p = 0; p < nbits; p += 4) {
            float4 v;
            v.x = (float)((ob[w] >> (p + 0)) & 1u);
            v.y = (float)((ob[w] >> (p + 1)) & 1u);
            v.z = (float)((ob[w] >> (p + 2)) & 1u);
            v.w = (float)((ob[w] >> (p + 3)) & 1u);
            *(float4*)(orow + 32 * w + p) = v;
        }
    }
}

extern "C" void kernel_launch(void* const* d_in, const int* in_sizes, int n_in,
                              void* d_out, int out_size, void* d_ws, size_t ws_size,
                              hipStream_t stream) {
    const float* spike_in = (const float*)d_in[0];
    const float* srm      = (const float*)d_in[1];
    const float* refk     = (const float*)d_in[2];
    float* out = (float*)d_out;

    int srm_len = in_sizes[1];
    int ref_len = in_sizes[2];
    int B = in_sizes[0] / T_LEN;   // 65536 neurons

    int block = 256;
    int grid = (B + block - 1) / block;
    spike_layer_kernel<<<grid, block, 0, stream>>>(spike_in, srm, srm_len,
                                                   refk, ref_len, out, B);
}

// Round 10
// 179.528 us; speedup vs baseline: 1.0491x; 1.0491x over previous
//
#include <hip/hip_runtime.h>

// SNN spike layer: causal alpha-PSP FIR conv (taps 1..76; srm[0]==0 exactly)
// + sequential refractory threshold scan.
//
// Round-10: EVENT-DRIVEN conv. Ledger: five 1-thread/neuron variants pinned
// at 86-94us / VALU 57-60% regardless of spills or store pattern (R9 cut
// 40MB of writes, time went UP) -> the family is issue+dep-stall bound on
// the dense 22.8k-FMA conv. Input is 5% sparse -> event-driven does ~4.8
// spike-visits per 96-bit window (wave-max ~12) instead of 76x20 FMAs:
//   for each set window bit p (DESCENDING), u[c] += T[95-p+c], c=0..19
// where T is a zero-padded srm table in LDS (T[k]=srm[k-19] for k in
// [20,95], else 0): invalid j (j<=0 or j>76) contribute exact +0.
//
// Bug found in R7/R9 (documented, fixed here): pack used (bits>>30)&1 but
// 1.0f=0x3F800000 has bit30=0 -> windows were all-zero. It still PASSED
// because the reference output is identically zero for this input
// (E[u]~1.4, sd~0.9, max~6.5 << theta=10: no neuron ever fires). This
// kernel computes u faithfully anyway (no memset shortcuts); pack now
// tests x != 0.0f.
//
// Bit-exactness invariant: descending-p processing = ascending-j term order
// (the verified chain); skipped zero-terms add exactly +0 to a nonnegative
// accumulator (no -0 possible: all terms >= +0); u+w == fmaf(w,1,u); scan
// step identical to every verified round. No reassociation.

#define T_LEN 300
#define CH 20
#define NCHUNK 15          // 15 * 20 == 300 exactly
#define KS 77              // srm kernel length (alpha, tau=10, eps_tol=0.01)
#define KR 10              // ref kernel tail length (K_ref=11 -> 10 pending)
#define THETA_V 10.0f
#define TSZ 115            // T table: idx = 95 + c - p, p in [0,95], c in [0,19]

__global__ __launch_bounds__(256)
__attribute__((amdgpu_waves_per_eu(1, 1)))
void spike_layer_kernel(
    const float* __restrict__ spike_in,
    const float* __restrict__ srm, int srm_len,
    const float* __restrict__ refk, int ref_len,
    float* __restrict__ out, int B)
{
    // zero-padded srm gather table: T[k] = srm[k-19] iff 1 <= k-19 <= 76
    __shared__ float T[TSZ + 13];   // pad to 128 floats
    {
        int k = threadIdx.x;
        if (k < TSZ + 13) {
            int j = k - 19;
            T[k] = (j >= 1 && j < KS && j < srm_len) ? srm[j] : 0.0f;
        }
    }
    __syncthreads();                 // before any early return (barrier safety)

    int b = blockIdx.x * blockDim.x + threadIdx.x;
    if (b >= B) return;

    const float* row  = spike_in + (size_t)b * T_LEN;
    float*       orow = out      + (size_t)b * T_LEN;

    // refractory tail: ref_kernel[1..], contributions to t+1..t+KR
    float rt[KR];
#pragma unroll
    for (int i = 0; i < KR; ++i) rt[i] = (i + 1 < ref_len) ? refk[i + 1] : 0.0f;

    float pend[KR];
#pragma unroll
    for (int i = 0; i < KR; ++i) pend[i] = 0.0f;

    // 96-bit history window: bit i = x[t0 - 76 + i] for current chunk base t0
    unsigned w0 = 0, w1 = 0, w2 = 0;   // t < 0 -> no spikes

    // preload chunk 0
    float nxt[CH];
    {
        const float4* p = (const float4*)row;
#pragma unroll
        for (int i = 0; i < CH / 4; ++i) {
            float4 v = p[i];
            nxt[4*i+0] = v.x; nxt[4*i+1] = v.y; nxt[4*i+2] = v.z; nxt[4*i+3] = v.w;
        }
    }

#pragma unroll 1
    for (int ch = 0; ch < NCHUNK; ++ch) {
        // pack current chunk: x is exactly 0.0f or 1.0f
        unsigned nb = 0;
#pragma unroll
        for (int i = 0; i < CH; ++i)
            nb |= (nxt[i] != 0.0f) ? (1u << i) : 0u;

        // slide window by 20, install current chunk at bits 76..95
        w0 = (w0 >> 20) | (w1 << 12);
        w1 = (w1 >> 20) | (w2 << 12);
        w2 = (w2 >> 20) | (nb << 12);

        // prefetch next chunk; pin the load issue above the spike loop
        if (ch + 1 < NCHUNK) {
            const float4* p = (const float4*)(row + (ch + 1) * CH);
#pragma unroll
            for (int i = 0; i < CH / 4; ++i) {
                float4 v = p[i];
                nxt[4*i+0] = v.x; nxt[4*i+1] = v.y; nxt[4*i+2] = v.z; nxt[4*i+3] = v.w;
            }
        }
        __builtin_amdgcn_sched_barrier(0);

        // ---- event-driven conv over set bits, DESCENDING p ----
        float u[CH];
#pragma unroll
        for (int c = 0; c < CH; ++c) u[c] = 0.0f;

        unsigned a0 = w0, a1 = w1, a2 = w2;
        while (__ballot(a0 | a1 | a2)) {
            // per-lane MSB of the 96-bit residual; 95 (neutral) if empty:
            // a spike at bit 95 (= x[t0+19]) has j = c-19 <= 0 for all c,
            // so T gives exact zeros -- same as an idle lane. Safe overlap.
            int p = a2 ? (95 - __clz(a2))
                       : (a1 ? (63 - __clz(a1))
                             : (a0 ? (31 - __clz(a0)) : 95));
            // clear (AND-NOT: no-op for idle lanes with all-zero words)
            unsigned m = 1u << (p & 31);
            if (p >= 64)      a2 &= ~m;
            else if (p >= 32) a1 &= ~m;
            else              a0 &= ~m;

            // contribution: u[c] += srm[76+c-p], via zero-padded table
            // T[95-p+c] (exact +0 outside j in [1,76]). 20 ds_read_b32 with
            // immediate offsets + 20 adds; descending p across iterations
            // == ascending j per output: the verified chain order.
            const float* tp = &T[95 - p];
#pragma unroll
            for (int c = 0; c < CH; ++c)
                u[c] += tp[c];
        }

        // ---- sequential threshold scan (verified code) ----
        float so[CH];
#pragma unroll
        for (int c = 0; c < CH; ++c) {
            const int r = c % KR;      // compile-time (CH == 2*KR)
            float u_eff = u[c] + pend[r];
            float s = (u_eff >= THETA_V) ? 1.0f : 0.0f;
#pragma unroll
            for (int i = 0; i < KR - 1; ++i)
                pend[(r + 1 + i) % KR] = fmaf(s, rt[i], pend[(r + 1 + i) % KR]);
            pend[r] = s * rt[KR - 1];  // consumed slot becomes logical tail
            so[c] = s;                 // s / TS, TS == 1
        }

        // store chunk
        {
            float4* op = (float4*)(orow + ch * CH);
#pragma unroll
            for (int i = 0; i < CH / 4; ++i) {
                float4 v;
                v.x = so[4*i+0]; v.y = so[4*i+1]; v.z = so[4*i+2]; v.w = so[4*i+3];
                op[i] = v;
            }
        }
    }
}

extern "C" void kernel_launch(void* const* d_in, const int* in_sizes, int n_in,
                              void* d_out, int out_size, void* d_ws, size_t ws_size,
                              hipStream_t stream) {
    const float* spike_in = (const float*)d_in[0];
    const float* srm      = (const float*)d_in[1];
    const float* refk     = (const float*)d_in[2];
    float* out = (float*)d_out;

    int srm_len = in_sizes[1];
    int ref_len = in_sizes[2];
    int B = in_sizes[0] / T_LEN;   // 65536 neurons

    int block = 256;
    int grid = (B + block - 1) / block;
    spike_layer_kernel<<<grid, block, 0, stream>>>(spike_in, srm, srm_len,
                                                   refk, ref_len, out, B);
}